// Round 1
// baseline (1376.544 us; speedup 1.0000x reference)
//
#include <hip/hip_runtime.h>

#define HIDDEN 30

// ---- sortable-uint encoding for float atomic max (handles negatives, -inf) ----
__device__ __forceinline__ unsigned enc_f(float f) {
    unsigned u = __float_as_uint(f);
    return (u & 0x80000000u) ? ~u : (u | 0x80000000u);
}
__device__ __forceinline__ float dec_f(unsigned u) {
    unsigned b = (u & 0x80000000u) ? (u ^ 0x80000000u) : ~u;
    return __uint_as_float(b);
}
#define ENC_NEGINF 0x007fffffu  // enc(-inf)

__global__ void k_fill_u32(unsigned* p, unsigned v, int n) {
    int i = blockIdx.x * blockDim.x + threadIdx.x;
    if (i < n) p[i] = v;
}

// histogram of col -> deg (float counts; exact for small degrees)
__global__ void k_hist(const int* __restrict__ col, float* deg, int E) {
    int e = blockIdx.x * blockDim.x + threadIdx.x;
    if (e < E) atomicAdd(&deg[col[e]], 1.0f);
}

// deg -> dis = rsqrt(deg + 1)   (+1 = self loop; always > 0)
__global__ void k_dis(float* deg, int N) {
    int i = blockIdx.x * blockDim.x + threadIdx.x;
    if (i < N) deg[i] = rsqrtf(deg[i] + 1.0f);
}

// x[N,128] @ W[128,30] -> out[N,30].  8 nodes/block, 30 threads/node.
__global__ void k_gemm0(const float* __restrict__ x, const float* __restrict__ W,
                        float* __restrict__ out, int N) {
    __shared__ float Ws[128 * HIDDEN];
    for (int i = threadIdx.x; i < 128 * HIDDEN; i += blockDim.x) Ws[i] = W[i];
    __syncthreads();
    int t = threadIdx.x;
    if (t >= 240) return;
    int n = blockIdx.x * 8 + t / HIDDEN;
    int h = t % HIDDEN;
    if (n >= N) return;
    const float4* xr = (const float4*)(x + (size_t)n * 128);
    float acc = 0.f;
#pragma unroll
    for (int f4 = 0; f4 < 32; ++f4) {
        float4 v = xr[f4];
        int f = f4 * 4;
        acc += v.x * Ws[(f + 0) * HIDDEN + h] + v.y * Ws[(f + 1) * HIDDEN + h] +
               v.z * Ws[(f + 2) * HIDDEN + h] + v.w * Ws[(f + 3) * HIDDEN + h];
    }
    out[(size_t)n * HIDDEN + h] = acc;
}

// in[N,30] @ W[30,30] -> out[N,30]
__global__ void k_gemm_small(const float* __restrict__ in, const float* __restrict__ W,
                             float* __restrict__ out, int N) {
    __shared__ float Ws[HIDDEN * HIDDEN];
    for (int i = threadIdx.x; i < HIDDEN * HIDDEN; i += blockDim.x) Ws[i] = W[i];
    __syncthreads();
    int t = threadIdx.x;
    if (t >= 240) return;
    int n = blockIdx.x * 8 + t / HIDDEN;
    int h = t % HIDDEN;
    if (n >= N) return;
    const float* r = in + (size_t)n * HIDDEN;
    float acc = 0.f;
#pragma unroll
    for (int k = 0; k < HIDDEN; ++k) acc += r[k] * Ws[k * HIDDEN + h];
    out[(size_t)n * HIDDEN + h] = acc;
}

// out[n][h] = tmp[n][h] * dis[n]^2 + b[h]   (self-loop message + bias)
__global__ void k_init(const float* __restrict__ tmp, const float* __restrict__ dis,
                       const float* __restrict__ b, float* __restrict__ out, int N) {
    int i = blockIdx.x * blockDim.x + threadIdx.x;
    if (i >= N * HIDDEN) return;
    int n = i / HIDDEN;
    int h = i - n * HIDDEN;
    float d = dis[n];
    out[i] = tmp[i] * d * d + b[h];
}

// per (edge, h): out[col][h] += tmp[row][h] * dis[row]*dis[col]
__global__ void k_edge(const int* __restrict__ row, const int* __restrict__ col,
                       const float* __restrict__ dis, const float* __restrict__ tmp,
                       float* __restrict__ out, int E) {
    long idx = (long)blockIdx.x * blockDim.x + threadIdx.x;
    int e = (int)(idx >> 5);
    int h = (int)(idx & 31);
    if (e >= E || h >= HIDDEN) return;
    int r = row[e], c = col[e];
    float w = dis[r] * dis[c];
    atomicAdd(&out[(size_t)c * HIDDEN + h], tmp[(size_t)r * HIDDEN + h] * w);
}

// optional relu (write back) + segment-max pool into encoded uint buffer
__global__ void k_relu_pool(float* __restrict__ hbuf, const int* __restrict__ batch,
                            unsigned* __restrict__ pooled, int N, int do_relu) {
    long idx = (long)blockIdx.x * blockDim.x + threadIdx.x;
    int n = (int)(idx >> 5);
    int h = (int)(idx & 31);
    if (n >= N || h >= HIDDEN) return;
    float v = hbuf[(size_t)n * HIDDEN + h];
    if (do_relu) {
        v = fmaxf(v, 0.0f);
        hbuf[(size_t)n * HIDDEN + h] = v;
    }
    int g = batch[n];
    atomicMax(&pooled[(size_t)g * HIDDEN + h], enc_f(v));
}

// readout [G,120] @ Wlin[120,2] + blin -> out[G,2]
__global__ void k_final(const unsigned* __restrict__ pooled, const float* __restrict__ Wlin,
                        const float* __restrict__ blin, float* __restrict__ out, int G) {
    int g = blockIdx.x * blockDim.x + threadIdx.x;
    if (g >= G) return;
    float a0 = blin[0], a1 = blin[1];
#pragma unroll
    for (int l = 0; l < 4; ++l) {
        for (int h = 0; h < HIDDEN; ++h) {
            unsigned u = pooled[((size_t)l * G + g) * HIDDEN + h];
            float v = dec_f(u);
            if (u == ENC_NEGINF) v = 0.0f;  // empty graph: -inf -> 0
            int k = l * HIDDEN + h;
            a0 += v * Wlin[k * 2 + 0];
            a1 += v * Wlin[k * 2 + 1];
        }
    }
    out[g * 2 + 0] = a0;
    out[g * 2 + 1] = a1;
}

static inline size_t align256(size_t x) { return (x + 255) & ~(size_t)255; }

extern "C" void kernel_launch(void* const* d_in, const int* in_sizes, int n_in,
                              void* d_out, int out_size, void* d_ws, size_t ws_size,
                              hipStream_t stream) {
    const float* x     = (const float*)d_in[0];
    const int*   ei    = (const int*)d_in[1];
    const int*   batch = (const int*)d_in[2];
    const float* W0 = (const float*)d_in[4];
    const float* b0 = (const float*)d_in[5];
    const float* W1 = (const float*)d_in[6];
    const float* b1 = (const float*)d_in[7];
    const float* W2 = (const float*)d_in[8];
    const float* b2 = (const float*)d_in[9];
    const float* W3 = (const float*)d_in[10];
    const float* b3 = (const float*)d_in[11];
    const float* Wlin = (const float*)d_in[12];
    const float* blin = (const float*)d_in[13];

    const int N = in_sizes[0] / 128;
    const int E = in_sizes[1] / 2;
    const int G = out_size / 2;
    const int* row = ei;
    const int* col = ei + E;

    char* ws = (char*)d_ws;
    float* dis = (float*)ws;                        // N floats (deg then dis in-place)
    size_t off = align256((size_t)N * 4);
    float* A = (float*)(ws + off);                  // N*30 floats (tmp = transform output)
    off += align256((size_t)N * HIDDEN * 4);
    float* B = (float*)(ws + off);                  // N*30 floats (h buffer)
    off += align256((size_t)N * HIDDEN * 4);
    unsigned* pooled = (unsigned*)(ws + off);       // 4*G*30 uints

    const float* Wl[4] = {W0, W1, W2, W3};
    const float* bl[4] = {b0, b1, b2, b3};

    // degree -> dis
    hipMemsetAsync(dis, 0, (size_t)N * 4, stream);
    k_hist<<<(E + 255) / 256, 256, 0, stream>>>(col, dis, E);
    k_dis<<<(N + 255) / 256, 256, 0, stream>>>(dis, N);

    // pooled init to enc(-inf)
    int pn = 4 * G * HIDDEN;
    k_fill_u32<<<(pn + 255) / 256, 256, 0, stream>>>(pooled, ENC_NEGINF, pn);

    long ethreads = (long)E * 32;
    int eblocks = (int)((ethreads + 255) / 256);
    long nthreads32 = (long)N * 32;
    int nblocks32 = (int)((nthreads32 + 255) / 256);

    for (int l = 0; l < 4; ++l) {
        if (l == 0) {
            k_gemm0<<<(N + 7) / 8, 256, 0, stream>>>(x, W0, A, N);
        } else {
            k_gemm_small<<<(N + 7) / 8, 256, 0, stream>>>(B, Wl[l], A, N);
        }
        k_init<<<(N * HIDDEN + 255) / 256, 256, 0, stream>>>(A, dis, bl[l], B, N);
        k_edge<<<eblocks, 256, 0, stream>>>(row, col, dis, A, B, E);
        k_relu_pool<<<nblocks32, 256, 0, stream>>>(B, batch, pooled + (size_t)l * G * HIDDEN,
                                                   N, l < 3 ? 1 : 0);
    }

    k_final<<<(G + 255) / 256, 256, 0, stream>>>(pooled, Wlin, blin, (float*)d_out, G);
}

// Round 6
// 829.944 us; speedup vs baseline: 1.6586x; 1.6586x over previous
//
#include <hip/hip_runtime.h>
#include <math.h>

#define HIDDEN 30

// ---------------- CSR construction ----------------

// histogram of col -> deg (u32)
__global__ void k_hist(const int* __restrict__ col, unsigned* __restrict__ deg, int E) {
    int e = blockIdx.x * blockDim.x + threadIdx.x;
    if (e < E) atomicAdd(&deg[col[e]], 1u);
}

// dis[n] = rsqrt(deg[n] + 1)   (+1 = self loop; always > 0)
__global__ void k_dis(const unsigned* __restrict__ deg, float* __restrict__ dis, int N) {
    int i = blockIdx.x * blockDim.x + threadIdx.x;
    if (i < N) dis[i] = rsqrtf((float)deg[i] + 1.0f);
}

// inclusive scan of deg in 1024-blocks; writes to inc (= rowptr+1); block totals to bsum
__global__ void k_scan_block(const unsigned* __restrict__ deg, unsigned* __restrict__ inc,
                             unsigned* __restrict__ bsum, int N) {
    __shared__ unsigned s[1024];
    int i = blockIdx.x * 1024 + threadIdx.x;
    unsigned v = (i < N) ? deg[i] : 0u;
    s[threadIdx.x] = v;
    __syncthreads();
    for (int off = 1; off < 1024; off <<= 1) {
        unsigned t = (threadIdx.x >= off) ? s[threadIdx.x - off] : 0u;
        __syncthreads();
        s[threadIdx.x] += t;
        __syncthreads();
    }
    if (i < N) inc[i] = s[threadIdx.x];
    if (threadIdx.x == 1023) bsum[blockIdx.x] = s[1023];
}

// inclusive scan of block sums (single block, nb <= 128)
__global__ void k_scan_bsums(unsigned* __restrict__ bsum, int nb) {
    __shared__ unsigned s[128];
    int i = threadIdx.x;
    s[i] = (i < nb) ? bsum[i] : 0u;
    __syncthreads();
    for (int off = 1; off < 128; off <<= 1) {
        unsigned t = (i >= off) ? s[i - off] : 0u;
        __syncthreads();
        s[i] += t;
        __syncthreads();
    }
    if (i < nb) bsum[i] = s[i];
}

// rowptr[i+1] += carry;  rowptr[0] = 0   (scan values already in rowptr[1..N])
__global__ void k_rowptr(const unsigned* __restrict__ bsum, unsigned* __restrict__ rowptr, int N) {
    int i = blockIdx.x * 1024 + threadIdx.x;
    if (i >= N) return;
    int blk = i >> 10;
    if (blk) rowptr[i + 1] += bsum[blk - 1];
    if (i == 0) rowptr[0] = 0u;
}

// src[rowptr[c] + rank] = row(e)
__global__ void k_scatter(const int* __restrict__ row, const int* __restrict__ col,
                          const unsigned* __restrict__ rowptr, unsigned* __restrict__ cnt,
                          int* __restrict__ src, int E) {
    int e = blockIdx.x * blockDim.x + threadIdx.x;
    if (e >= E) return;
    int c = col[e];
    unsigned p = rowptr[c] + atomicAdd(&cnt[c], 1u);
    src[p] = row[e];
}

// per-graph node ranges from sorted batch
__global__ void k_gstart(const int* __restrict__ batch, int* __restrict__ gstart, int N, int G) {
    int i = blockIdx.x * blockDim.x + threadIdx.x;
    if (i >= N) return;
    int b = batch[i];
    if (i == 0) {
        for (int g = 0; g <= b; ++g) gstart[g] = 0;
    } else {
        int p = batch[i - 1];
        if (p != b) for (int g = p + 1; g <= b; ++g) gstart[g] = i;
    }
    if (i == N - 1) {
        for (int g = b + 1; g <= G; ++g) gstart[g] = N;
    }
}

// ---------------- per-layer kernels ----------------

// S[n][h] = (x[n] . W[:,h]) * dis[n]     x:[N,128]
__global__ void k_transform0(const float* __restrict__ x, const float* __restrict__ W,
                             const float* __restrict__ dis, float* __restrict__ S, int N) {
    __shared__ float Ws[128 * HIDDEN];
    for (int i = threadIdx.x; i < 128 * HIDDEN; i += blockDim.x) Ws[i] = W[i];
    __syncthreads();
    int t = threadIdx.x;
    if (t >= 240) return;
    int n = blockIdx.x * 8 + t / HIDDEN;
    int h = t % HIDDEN;
    if (n >= N) return;
    const float4* xr = (const float4*)(x + (size_t)n * 128);
    float acc = 0.f;
#pragma unroll
    for (int f4 = 0; f4 < 32; ++f4) {
        float4 v = xr[f4];
        int f = f4 * 4;
        acc += v.x * Ws[(f + 0) * HIDDEN + h] + v.y * Ws[(f + 1) * HIDDEN + h] +
               v.z * Ws[(f + 2) * HIDDEN + h] + v.w * Ws[(f + 3) * HIDDEN + h];
    }
    S[(size_t)n * HIDDEN + h] = acc * dis[n];
}

// S[n][h] = (in[n] . W[:,h]) * dis[n]    in:[N,30]
__global__ void k_transform_small(const float* __restrict__ in, const float* __restrict__ W,
                                  const float* __restrict__ dis, float* __restrict__ S, int N) {
    __shared__ float Ws[HIDDEN * HIDDEN];
    for (int i = threadIdx.x; i < HIDDEN * HIDDEN; i += blockDim.x) Ws[i] = W[i];
    __syncthreads();
    int t = threadIdx.x;
    if (t >= 240) return;
    int n = blockIdx.x * 8 + t / HIDDEN;
    int h = t % HIDDEN;
    if (n >= N) return;
    const float* r = in + (size_t)n * HIDDEN;
    float acc = 0.f;
#pragma unroll
    for (int k = 0; k < HIDDEN; ++k) acc += r[k] * Ws[k * HIDDEN + h];
    S[(size_t)n * HIDDEN + h] = acc * dis[n];
}

// B[n][h] = act( dis[n] * (S[n][h] + sum_{r in adj(n)} S[r][h]) + b[h] )
// 2 nodes per wave: lanes 0..31 -> node A, 32..63 -> node B; h = lane & 31
__global__ void k_agg(const unsigned* __restrict__ rowptr, const int* __restrict__ src,
                      const float* __restrict__ S, const float* __restrict__ dis,
                      const float* __restrict__ b, float* __restrict__ B, int N, int do_relu) {
    int t = threadIdx.x;
    int h = t & 31;
    int n = blockIdx.x * 8 + (t >> 5);
    if (n >= N) return;
    bool hv = h < HIDDEN;
    float acc = hv ? S[(size_t)n * HIDDEN + h] : 0.f;  // self-loop term
    unsigned beg = rowptr[n], end = rowptr[n + 1];
    for (unsigned j = beg; j < end; ++j) {
        int r = src[j];
        if (hv) acc += S[(size_t)r * HIDDEN + h];
    }
    if (!hv) return;
    float v = dis[n] * acc + b[h];
    if (do_relu) v = fmaxf(v, 0.0f);
    B[(size_t)n * HIDDEN + h] = v;
}

// deterministic per-graph max pool; one wave per graph (2 nodes at a time)
__global__ void k_pool(const float* __restrict__ B, const int* __restrict__ gstart,
                       float* __restrict__ pooled, int G) {
    int g = blockIdx.x * 4 + (threadIdx.x >> 6);
    if (g >= G) return;
    int lane = threadIdx.x & 63;
    int h = lane & 31;
    int sub = lane >> 5;
    int beg = gstart[g], end = gstart[g + 1];
    float m = -INFINITY;
    if (h < HIDDEN) {
        for (int i = beg + sub; i < end; i += 2) m = fmaxf(m, B[(size_t)i * HIDDEN + h]);
    }
    float o = __shfl_down(m, 32);
    m = fmaxf(m, o);
    if (sub == 0 && h < HIDDEN) pooled[(size_t)g * HIDDEN + h] = (end > beg) ? m : 0.0f;
}

// readout [G,120] @ Wlin[120,2] + blin -> out[G,2]
__global__ void k_final(const float* __restrict__ pooled, const float* __restrict__ Wlin,
                        const float* __restrict__ blin, float* __restrict__ out, int G) {
    int g = blockIdx.x * blockDim.x + threadIdx.x;
    if (g >= G) return;
    float a0 = blin[0], a1 = blin[1];
#pragma unroll
    for (int l = 0; l < 4; ++l) {
        for (int h = 0; h < HIDDEN; ++h) {
            float v = pooled[((size_t)l * G + g) * HIDDEN + h];
            int k = l * HIDDEN + h;
            a0 += v * Wlin[k * 2 + 0];
            a1 += v * Wlin[k * 2 + 1];
        }
    }
    out[g * 2 + 0] = a0;
    out[g * 2 + 1] = a1;
}

static inline size_t align256(size_t x) { return (x + 255) & ~(size_t)255; }

extern "C" void kernel_launch(void* const* d_in, const int* in_sizes, int n_in,
                              void* d_out, int out_size, void* d_ws, size_t ws_size,
                              hipStream_t stream) {
    const float* x     = (const float*)d_in[0];
    const int*   ei    = (const int*)d_in[1];
    const int*   batch = (const int*)d_in[2];
    const float* W0 = (const float*)d_in[4];
    const float* b0 = (const float*)d_in[5];
    const float* W1 = (const float*)d_in[6];
    const float* b1 = (const float*)d_in[7];
    const float* W2 = (const float*)d_in[8];
    const float* b2 = (const float*)d_in[9];
    const float* W3 = (const float*)d_in[10];
    const float* b3 = (const float*)d_in[11];
    const float* Wlin = (const float*)d_in[12];
    const float* blin = (const float*)d_in[13];

    const int N = in_sizes[0] / 128;
    const int E = in_sizes[1] / 2;
    const int G = out_size / 2;
    const int* row = ei;
    const int* col = ei + E;

    char* ws = (char*)d_ws;
    size_t off = 0;
    unsigned* deg    = (unsigned*)(ws + off); off += align256((size_t)N * 4);
    unsigned* cnt    = (unsigned*)(ws + off); off += align256((size_t)N * 4);
    unsigned* rowptr = (unsigned*)(ws + off); off += align256(((size_t)N + 1) * 4);
    unsigned* bsum   = (unsigned*)(ws + off); off += align256(128 * 4);
    int*      gstart = (int*)(ws + off);      off += align256(((size_t)G + 1) * 4);
    float*    dis    = (float*)(ws + off);    off += align256((size_t)N * 4);
    int*      src    = (int*)(ws + off);      off += align256((size_t)E * 4);
    float*    S      = (float*)(ws + off);    off += align256((size_t)N * HIDDEN * 4);
    float*    B      = (float*)(ws + off);    off += align256((size_t)N * HIDDEN * 4);
    float*    pooled = (float*)(ws + off);    off += align256((size_t)4 * G * HIDDEN * 4);

    const float* Wl[4] = {W0, W1, W2, W3};
    const float* bl[4] = {b0, b1, b2, b3};

    // ---- CSR build (once; reused by all 4 layers) ----
    // EXACT-size zeroing: workspace is re-poisoned 0xAA before every launch.
    hipMemsetAsync(deg, 0, (size_t)N * 4, stream);
    hipMemsetAsync(cnt, 0, (size_t)N * 4, stream);
    k_hist<<<(E + 255) / 256, 256, 0, stream>>>(col, deg, E);
    k_dis<<<(N + 255) / 256, 256, 0, stream>>>(deg, dis, N);
    int nb = (N + 1023) / 1024;
    k_scan_block<<<nb, 1024, 0, stream>>>(deg, rowptr + 1, bsum, N);
    k_scan_bsums<<<1, 128, 0, stream>>>(bsum, nb);
    k_rowptr<<<nb, 1024, 0, stream>>>(bsum, rowptr, N);
    k_scatter<<<(E + 255) / 256, 256, 0, stream>>>(row, col, rowptr, cnt, src, E);
    k_gstart<<<(N + 255) / 256, 256, 0, stream>>>(batch, gstart, N, G);

    // ---- 4 GCN layers ----
    int nblk8 = (N + 7) / 8;
    for (int l = 0; l < 4; ++l) {
        if (l == 0) k_transform0<<<nblk8, 256, 0, stream>>>(x, W0, dis, S, N);
        else        k_transform_small<<<nblk8, 256, 0, stream>>>(B, Wl[l], dis, S, N);
        k_agg<<<nblk8, 256, 0, stream>>>(rowptr, src, S, dis, bl[l], B, N, l < 3 ? 1 : 0);
        k_pool<<<(G + 3) / 4, 256, 0, stream>>>(B, gstart, pooled + (size_t)l * G * HIDDEN, G);
    }

    k_final<<<(G + 255) / 256, 256, 0, stream>>>(pooled, Wlin, blin, (float*)d_out, G);
}

// Round 8
// 652.259 us; speedup vs baseline: 2.1104x; 1.2724x over previous
//
#include <hip/hip_runtime.h>
#include <math.h>

#define HIDDEN 30
#define SP 32  // padded row stride (floats) -> 128B rows

// ---------------- CSR construction ----------------

__global__ void k_hist(const int* __restrict__ col, unsigned* __restrict__ deg, int E) {
    int e = blockIdx.x * blockDim.x + threadIdx.x;
    if (e < E) atomicAdd(&deg[col[e]], 1u);
}

__global__ void k_dis(const unsigned* __restrict__ deg, float* __restrict__ dis, int N) {
    int i = blockIdx.x * blockDim.x + threadIdx.x;
    if (i < N) dis[i] = rsqrtf((float)deg[i] + 1.0f);
}

// inclusive scan of deg in 1024-blocks; writes to rowptr+1; block totals to bsum
__global__ void k_scan_block(const unsigned* __restrict__ deg, unsigned* __restrict__ inc,
                             unsigned* __restrict__ bsum, int N) {
    __shared__ unsigned s[1024];
    int i = blockIdx.x * 1024 + threadIdx.x;
    unsigned v = (i < N) ? deg[i] : 0u;
    s[threadIdx.x] = v;
    __syncthreads();
    for (int off = 1; off < 1024; off <<= 1) {
        unsigned t = (threadIdx.x >= off) ? s[threadIdx.x - off] : 0u;
        __syncthreads();
        s[threadIdx.x] += t;
        __syncthreads();
    }
    if (i < N) inc[i] = s[threadIdx.x];
    if (threadIdx.x == 1023) bsum[blockIdx.x] = s[1023];
}

__global__ void k_scan_bsums(unsigned* __restrict__ bsum, int nb) {
    __shared__ unsigned s[128];
    int i = threadIdx.x;
    s[i] = (i < nb) ? bsum[i] : 0u;
    __syncthreads();
    for (int off = 1; off < 128; off <<= 1) {
        unsigned t = (i >= off) ? s[i - off] : 0u;
        __syncthreads();
        s[i] += t;
        __syncthreads();
    }
    if (i < nb) bsum[i] = s[i];
}

// rowptr[i+1] += carry;  rowptr[0] = 0
__global__ void k_rowptr(const unsigned* __restrict__ bsum, unsigned* __restrict__ rowptr, int N) {
    int i = blockIdx.x * 1024 + threadIdx.x;
    if (i >= N) return;
    int blk = i >> 10;
    if (blk) rowptr[i + 1] += bsum[blk - 1];
    if (i == 0) rowptr[0] = 0u;
}

// cnt[i] = rowptr[i]  (so scatter needs only ONE atomic, no rowptr gather)
__global__ void k_cnt_copy(const unsigned* __restrict__ rowptr, unsigned* __restrict__ cnt, int N) {
    int i = blockIdx.x * blockDim.x + threadIdx.x;
    if (i < N) cnt[i] = rowptr[i];
}

// src[slot] = row(e), slot = cnt[c]++
__global__ void k_scatter(const int* __restrict__ row, const int* __restrict__ col,
                          unsigned* __restrict__ cnt, int* __restrict__ src, int E) {
    int e = blockIdx.x * blockDim.x + threadIdx.x;
    if (e >= E) return;
    int c = col[e];
    unsigned p = atomicAdd(&cnt[c], 1u);
    src[p] = row[e];
}

// per-graph node ranges from sorted batch
__global__ void k_gstart(const int* __restrict__ batch, int* __restrict__ gstart, int N, int G) {
    int i = blockIdx.x * blockDim.x + threadIdx.x;
    if (i >= N) return;
    int b = batch[i];
    if (i == 0) {
        for (int g = 0; g <= b; ++g) gstart[g] = 0;
    } else {
        int p = batch[i - 1];
        if (p != b) for (int g = p + 1; g <= b; ++g) gstart[g] = i;
    }
    if (i == N - 1) {
        for (int g = b + 1; g <= G; ++g) gstart[g] = N;
    }
}

// ---------------- per-layer kernels ----------------

// S[n][h] = (x[n] . W[:,h]) * dis[n]; x:[N,128], S padded to SP=32, pads = 0
__global__ void k_transform0(const float* __restrict__ x, const float* __restrict__ W,
                             const float* __restrict__ dis, float* __restrict__ S, int N) {
    __shared__ float Ws[128 * HIDDEN];
    __shared__ float Xs[8 * 128];
    for (int i = threadIdx.x; i < 128 * HIDDEN; i += 256) Ws[i] = W[i];
    int nb = blockIdx.x * 8;
    for (int i = threadIdx.x; i < 8 * 128; i += 256) {
        int nn = nb + (i >> 7);
        Xs[i] = (nn < N) ? x[(size_t)nn * 128 + (i & 127)] : 0.f;
    }
    __syncthreads();
    int nl = threadIdx.x >> 5, h = threadIdx.x & 31;
    int n = nb + nl;
    if (n >= N) return;
    float acc = 0.f;
    if (h < HIDDEN) {
        const float* xr = &Xs[nl * 128];
#pragma unroll 8
        for (int f = 0; f < 128; ++f) acc += xr[f] * Ws[f * HIDDEN + h];
        acc *= dis[n];
    }
    S[(size_t)n * SP + h] = (h < HIDDEN) ? acc : 0.f;
}

// S[n][h] = (in[n] . W[:,h]) * dis[n]; in padded SP, S padded SP
__global__ void k_transform_small(const float* __restrict__ in, const float* __restrict__ W,
                                  const float* __restrict__ dis, float* __restrict__ S, int N) {
    __shared__ float Ws[HIDDEN * HIDDEN];
    __shared__ float Bs[8 * SP];
    for (int i = threadIdx.x; i < HIDDEN * HIDDEN; i += 256) Ws[i] = W[i];
    int nb = blockIdx.x * 8;
    {
        int i = threadIdx.x;  // 256 threads = 8*SP exactly
        int nn = nb + (i >> 5);
        Bs[i] = (nn < N) ? in[(size_t)nn * SP + (i & 31)] : 0.f;
    }
    __syncthreads();
    int nl = threadIdx.x >> 5, h = threadIdx.x & 31;
    int n = nb + nl;
    if (n >= N) return;
    float acc = 0.f;
    if (h < HIDDEN) {
        const float* r = &Bs[nl * SP];
#pragma unroll
        for (int k = 0; k < HIDDEN; ++k) acc += r[k] * Ws[k * HIDDEN + h];
        acc *= dis[n];
    }
    S[(size_t)n * SP + h] = (h < HIDDEN) ? acc : 0.f;
}

// one wave per node: 8 lane-groups x float4 -> 8 neighbor rows (1KB) in flight/iter
// B[n] = act( dis[n] * (S[n] + sum_{r in adj(n)} S[r]) + b )
__global__ void k_agg(const unsigned* __restrict__ rowptr, const int* __restrict__ src,
                      const float4* __restrict__ S4, const float* __restrict__ dis,
                      const float* __restrict__ b, float4* __restrict__ B4, int N, int do_relu) {
    int w = threadIdx.x >> 6;
    int lane = threadIdx.x & 63;
    int n = blockIdx.x * 4 + w;
    if (n >= N) return;
    int g = lane >> 3, s = lane & 7;
    float ax = 0.f, ay = 0.f, az = 0.f, aw = 0.f;
    if (g == 0) {  // self-loop term
        float4 v = S4[(size_t)n * 8 + s];
        ax = v.x; ay = v.y; az = v.z; aw = v.w;
    }
    unsigned beg = rowptr[n], end = rowptr[n + 1];
    for (unsigned j = beg + g; j < end; j += 8) {
        int r = src[j];
        float4 v = S4[(size_t)r * 8 + s];
        ax += v.x; ay += v.y; az += v.z; aw += v.w;
    }
    // reduce across the 8 lane-groups (xor butterfly on lane bits 3..5)
    for (int off = 8; off < 64; off <<= 1) {
        ax += __shfl_xor(ax, off);
        ay += __shfl_xor(ay, off);
        az += __shfl_xor(az, off);
        aw += __shfl_xor(aw, off);
    }
    if (g == 0) {
        float d = dis[n];
        int h = s * 4;
        float o0 = (h + 0 < HIDDEN) ? d * ax + b[h + 0] : 0.f;
        float o1 = (h + 1 < HIDDEN) ? d * ay + b[h + 1] : 0.f;
        float o2 = (h + 2 < HIDDEN) ? d * az + b[h + 2] : 0.f;
        float o3 = (h + 3 < HIDDEN) ? d * aw + b[h + 3] : 0.f;
        if (do_relu) {
            o0 = fmaxf(o0, 0.f); o1 = fmaxf(o1, 0.f);
            o2 = fmaxf(o2, 0.f); o3 = fmaxf(o3, 0.f);
        }
        B4[(size_t)n * 8 + s] = make_float4(o0, o1, o2, o3);
    }
}

// deterministic per-graph max pool (B padded SP); 2 nodes per wave
__global__ void k_pool(const float* __restrict__ B, const int* __restrict__ gstart,
                       float* __restrict__ pooled, int G) {
    int g = blockIdx.x * 4 + (threadIdx.x >> 6);
    if (g >= G) return;
    int lane = threadIdx.x & 63;
    int h = lane & 31;
    int sub = lane >> 5;
    int beg = gstart[g], end = gstart[g + 1];
    float m = -INFINITY;
    if (h < HIDDEN) {
        for (int i = beg + sub; i < end; i += 2) m = fmaxf(m, B[(size_t)i * SP + h]);
    }
    float o = __shfl_down(m, 32);
    m = fmaxf(m, o);
    if (sub == 0 && h < HIDDEN) pooled[(size_t)g * HIDDEN + h] = (end > beg) ? m : 0.0f;
}

// readout [G,120] @ Wlin[120,2] + blin -> out[G,2]
__global__ void k_final(const float* __restrict__ pooled, const float* __restrict__ Wlin,
                        const float* __restrict__ blin, float* __restrict__ out, int G) {
    int g = blockIdx.x * blockDim.x + threadIdx.x;
    if (g >= G) return;
    float a0 = blin[0], a1 = blin[1];
#pragma unroll
    for (int l = 0; l < 4; ++l) {
        for (int h = 0; h < HIDDEN; ++h) {
            float v = pooled[((size_t)l * G + g) * HIDDEN + h];
            int k = l * HIDDEN + h;
            a0 += v * Wlin[k * 2 + 0];
            a1 += v * Wlin[k * 2 + 1];
        }
    }
    out[g * 2 + 0] = a0;
    out[g * 2 + 1] = a1;
}

static inline size_t align256(size_t x) { return (x + 255) & ~(size_t)255; }

extern "C" void kernel_launch(void* const* d_in, const int* in_sizes, int n_in,
                              void* d_out, int out_size, void* d_ws, size_t ws_size,
                              hipStream_t stream) {
    const float* x     = (const float*)d_in[0];
    const int*   ei    = (const int*)d_in[1];
    const int*   batch = (const int*)d_in[2];
    const float* W0 = (const float*)d_in[4];
    const float* b0 = (const float*)d_in[5];
    const float* W1 = (const float*)d_in[6];
    const float* b1 = (const float*)d_in[7];
    const float* W2 = (const float*)d_in[8];
    const float* b2 = (const float*)d_in[9];
    const float* W3 = (const float*)d_in[10];
    const float* b3 = (const float*)d_in[11];
    const float* Wlin = (const float*)d_in[12];
    const float* blin = (const float*)d_in[13];

    const int N = in_sizes[0] / 128;
    const int E = in_sizes[1] / 2;
    const int G = out_size / 2;
    const int* row = ei;
    const int* col = ei + E;

    char* ws = (char*)d_ws;
    size_t off = 0;
    unsigned* deg    = (unsigned*)(ws + off); off += align256((size_t)N * 4);
    unsigned* cnt    = (unsigned*)(ws + off); off += align256((size_t)N * 4);
    unsigned* rowptr = (unsigned*)(ws + off); off += align256(((size_t)N + 1) * 4);
    unsigned* bsum   = (unsigned*)(ws + off); off += align256(128 * 4);
    int*      gstart = (int*)(ws + off);      off += align256(((size_t)G + 1) * 4);
    float*    dis    = (float*)(ws + off);    off += align256((size_t)N * 4);
    int*      src    = (int*)(ws + off);      off += align256((size_t)E * 4);
    float*    S      = (float*)(ws + off);    off += align256((size_t)N * SP * 4);
    float*    B      = (float*)(ws + off);    off += align256((size_t)N * SP * 4);
    float*    pooled = (float*)(ws + off);    off += align256((size_t)4 * G * HIDDEN * 4);

    const float* Wl[4] = {W0, W1, W2, W3};
    const float* bl[4] = {b0, b1, b2, b3};

    // ---- CSR build (once; reused by all 4 layers) ----
    hipMemsetAsync(deg, 0, (size_t)N * 4, stream);  // exact-size: ws is re-poisoned 0xAA
    k_hist<<<(E + 255) / 256, 256, 0, stream>>>(col, deg, E);
    k_dis<<<(N + 255) / 256, 256, 0, stream>>>(deg, dis, N);
    int nb = (N + 1023) / 1024;
    k_scan_block<<<nb, 1024, 0, stream>>>(deg, rowptr + 1, bsum, N);
    k_scan_bsums<<<1, 128, 0, stream>>>(bsum, nb);
    k_rowptr<<<nb, 1024, 0, stream>>>(bsum, rowptr, N);
    k_cnt_copy<<<(N + 255) / 256, 256, 0, stream>>>(rowptr, cnt, N);
    k_scatter<<<(E + 255) / 256, 256, 0, stream>>>(row, col, cnt, src, E);
    k_gstart<<<(N + 255) / 256, 256, 0, stream>>>(batch, gstart, N, G);

    // ---- 4 GCN layers ----
    int nblk8 = (N + 7) / 8;
    int nblk4 = (N + 3) / 4;
    for (int l = 0; l < 4; ++l) {
        if (l == 0) k_transform0<<<nblk8, 256, 0, stream>>>(x, W0, dis, S, N);
        else        k_transform_small<<<nblk8, 256, 0, stream>>>(B, Wl[l], dis, S, N);
        k_agg<<<nblk4, 256, 0, stream>>>(rowptr, src, (const float4*)S, dis, bl[l],
                                         (float4*)B, N, l < 3 ? 1 : 0);
        k_pool<<<(G + 3) / 4, 256, 0, stream>>>(B, gstart, pooled + (size_t)l * G * HIDDEN, G);
    }

    k_final<<<(G + 255) / 256, 256, 0, stream>>>(pooled, Wlin, blin, (float*)d_out, G);
}